// Round 4
// baseline (2125.476 us; speedup 1.0000x reference)
//
#include <hip/hip_runtime.h>
#include <hip/hip_fp16.h>

#define NN 883
#define NP 896
#define DD 64
#define BB 32
#define LL 12
#define HH 12
#define MM 5
#define KBIG 3584          // 4*NP
#define ZSL (32*896*64)    // eoh slice elems

typedef _Float16 f16;
typedef _Float16 f16x4 __attribute__((ext_vector_type(4)));
typedef _Float16 f16x8 __attribute__((ext_vector_type(8)));
typedef float    f32x4 __attribute__((ext_vector_type(4)));

#define GLL16(G, L) __builtin_amdgcn_global_load_lds((const __attribute__((address_space(1))) void*)(G), (__attribute__((address_space(3))) void*)(L), 16, 0, 0)

// ---------- prep: row/col inverse sums ----------
__global__ __launch_bounds__(256) void k_sums(const float* __restrict__ A,
                                              float* __restrict__ invr,
                                              float* __restrict__ invc) {
  int bx = blockIdx.x, tid = threadIdx.x, lane = tid & 63, w = tid >> 6;
  if (bx < 221) {
    int row = bx * 4 + w;
    float s = 0.f;
    if (row < NN) for (int i = lane; i < NN; i += 64) s += A[(size_t)row * NN + i];
    #pragma unroll
    for (int st = 32; st; st >>= 1) s += __shfl_xor(s, st);
    if (lane == 0 && row < NN) invr[row] = 1.0f / s;
  } else {
    int cb = (bx - 221) * 64; int c = cb + lane; int g = w;
    float s = 0.f;
    if (c < NN) for (int r = g; r < NN; r += 4) s += A[(size_t)r * NN + c];
    __shared__ float red2[4][64];
    red2[g][lane] = s; __syncthreads();
    if (tid < 64 && (cb + tid) < NN)
      invc[cb + tid] = 1.0f / (red2[0][tid] + red2[1][tid] + red2[2][tid] + red2[3][tid]);
  }
}

// ---------- prep: Sbig blocks 0,2 + S1T,S2T ----------
__global__ __launch_bounds__(256) void k_sprep2(const float* __restrict__ A,
                                                const float* __restrict__ invr,
                                                const float* __restrict__ invc,
                                                f16* __restrict__ Sbig,
                                                f16* __restrict__ S1T,
                                                f16* __restrict__ S2T) {
  int r0 = blockIdx.y * 64, c0 = blockIdx.x * 64;
  int tid = threadIdx.x, lane = tid & 63, g = tid >> 6;
  __shared__ float tl[64][65];
  for (int i = g; i < 64; i += 4) {
    int r = r0 + i, c = c0 + lane;
    tl[i][lane] = (r < NN && c < NN) ? A[(size_t)r * NN + c] : 0.f;
  }
  __syncthreads();
  for (int i = g; i < 64; i += 4) {
    float v = tl[i][lane];
    int r = r0 + i, c = c0 + lane;
    Sbig[(size_t)r * KBIG + 2 * NP + c] = (f16)(v * invc[c]);   // S2[m=r][k=c]
    S1T[(size_t)r * NP + c] = (f16)(v * invr[r]);
  }
  for (int i = g; i < 64; i += 4) {
    float v = tl[lane][i];                                      // = A[r0+lane][c0+i]
    int m = c0 + i, k = r0 + lane;
    Sbig[(size_t)m * KBIG + k] = (f16)(v * invr[k]);            // S1
    S2T[(size_t)m * NP + k] = (f16)(v * invc[m]);
  }
}

// ---------- prep: Sbig blocks 1,3 = 2*S^2 ----------
__global__ __launch_bounds__(256) void k_ssq(f16* __restrict__ Sbig,
                                             const f16* __restrict__ S1T,
                                             const f16* __restrict__ S2T) {
  int c = blockIdx.z;
  const f16* Bt = c ? S2T : S1T;
  size_t aOff = (size_t)c * 2 * NP;
  int br = blockIdx.x * 128, c0 = blockIdx.y * 128;
  int tid = threadIdx.x;
  __shared__ f16 lA[128 * 32], lB[128 * 32];
  int lane = tid & 63, w = tid >> 6;
  int wr = (w >> 1) * 64, wc = (w & 1) * 64;
  int l15 = lane & 15, k8 = (lane >> 4) * 8;
  f32x4 acc[4][4] = {};
  for (int ks = 0; ks < NP; ks += 32) {
    __syncthreads();
    #pragma unroll
    for (int j = 0; j < 2; j++) {
      int idx = tid + j * 256;
      int row = idx >> 2, c8 = idx & 3;
      *(f16x8*)&lA[row * 32 + c8 * 8] = *(const f16x8*)(Sbig + (size_t)(br + row) * KBIG + aOff + ks + c8 * 8);
      *(f16x8*)&lB[row * 32 + c8 * 8] = *(const f16x8*)(Bt + (size_t)(c0 + row) * NP + ks + c8 * 8);
    }
    __syncthreads();
    f16x8 af[4], bf[4];
    #pragma unroll
    for (int fr = 0; fr < 4; fr++) af[fr] = *(const f16x8*)&lA[(wr + fr * 16 + l15) * 32 + k8];
    #pragma unroll
    for (int fc = 0; fc < 4; fc++) bf[fc] = *(const f16x8*)&lB[(wc + fc * 16 + l15) * 32 + k8];
    #pragma unroll
    for (int fr = 0; fr < 4; fr++)
      #pragma unroll
      for (int fc = 0; fc < 4; fc++)
        acc[fr][fc] = __builtin_amdgcn_mfma_f32_16x16x32_f16(af[fr], bf[fc], acc[fr][fc], 0, 0, 0);
  }
  size_t cOff = (size_t)(2 * c + 1) * NP;
  #pragma unroll
  for (int fr = 0; fr < 4; fr++)
    #pragma unroll
    for (int fc = 0; fc < 4; fc++) {
      int mmb = br + wr + fr * 16 + (lane >> 4) * 4;
      int ncol = c0 + wc + fc * 16 + l15;
      #pragma unroll
      for (int r = 0; r < 4; r++)
        Sbig[(size_t)(mmb + r) * KBIG + cOff + ncol] = (f16)(2.0f * acc[fr][fc][r]);
    }
}

// ---------- prep: W reorg + rank1 + rdot ----------
__global__ __launch_bounds__(256) void k_wprep(
    const float* __restrict__ egw, const float* __restrict__ dgw,
    const float* __restrict__ emw, const float* __restrict__ emb,
    const float* __restrict__ eR,  const float* __restrict__ dR,
    const float* __restrict__ eaw, const float* __restrict__ daw,
    f16* __restrict__ W2te, f16* __restrict__ W2td,
    float* __restrict__ uv, float* __restrict__ rdot) {
  int bx = blockIdx.x, tid = threadIdx.x;
  if (bx < 96) {
    int ph = bx / 48, k = (bx / 8) % 6, part = bx & 7;
    const float* R  = ph ? dR : eR;
    const float* aw = ph ? daw : eaw;
    const float* Rk = R + (size_t)k * NN * DD;
    int base = part * 7064;
    float s = 0.f;
    for (int i = base + tid; i < base + 7064; i += 256) s += Rk[i] * aw[i];
    __shared__ float red[256];
    red[tid] = s; __syncthreads();
    for (int st = 128; st; st >>= 1) { if (tid < st) red[tid] += red[tid + st]; __syncthreads(); }
    if (tid == 0) atomicAdd(&rdot[ph * 6 + k], red[0]);
  } else if (bx == 96) {
    // uv: 4 f-subgroups x 64 d, LDS reduce (cuts serial-load chain 64 -> 16)
    __shared__ float ru[4][64], rv[4][64];
    int g = tid >> 6, d = tid & 63;
    for (int m = 0; m < 5; m++) {
      float u = 0.f, v = 0.f;
      for (int f = g; f < 64; f += 4) {
        float w = egw[(size_t)(f * MM + m) * DD + d];
        u += emw[f] * w;
        v += emb[f] * w;
      }
      ru[g][d] = u; rv[g][d] = v; __syncthreads();
      if (tid < 64) {
        uv[m * 64 + tid] = ru[0][tid] + ru[1][tid] + ru[2][tid] + ru[3][tid];
        uv[320 + m * 64 + tid] = rv[0][tid] + rv[1][tid] + rv[2][tid] + rv[3][tid];
      }
      __syncthreads();
    }
  } else if (bx < 177) {
    int idx = (bx - 97) * 256 + tid;            // W2te[m][d][kf], f=64+kf
    int m = idx >> 12, d = (idx >> 6) & 63, kf = idx & 63;
    W2te[idx] = (f16)egw[(size_t)((64 + kf) * MM + m) * DD + d];
  } else {
    int idx = (bx - 177) * 256 + tid;           // W2td[m][d][kf], f=kf
    int m = idx >> 13, d = (idx >> 7) & 63, kf = idx & 127;
    W2td[idx] = (f16)dgw[(size_t)(kf * MM + m) * DD + d];
  }
}

// ---------- init: zcat(0), wf(0) ----------
__global__ __launch_bounds__(256) void k_z0(const float* __restrict__ hist,
                                            const float* __restrict__ uv,
                                            f16* __restrict__ zout,
                                            f16* __restrict__ wfout) {
  int col = blockIdx.x;               // b*64+d
  int b = col >> 6, d = col & 63;
  float u[5], v[5];
  #pragma unroll
  for (int m = 0; m < 5; m++) { u[m] = uv[m * 64 + d]; v[m] = uv[320 + m * 64 + d]; }
  for (int n = threadIdx.x; n < NP; n += 256) {
    bool valid = n < NN;
    float hv = valid ? hist[(size_t)b * LL * NN + n] : 0.f;
    #pragma unroll
    for (int m = 1; m < 5; m++)
      zout[(size_t)col * KBIG + (m - 1) * NP + n] = valid ? (f16)(hv * u[m] + v[m]) : (f16)0.f;
    wfout[(size_t)col * NP + n] = valid ?
      (f16)((hv * u[0] + v[0]) - (hv * u[2] + v[2]) - (hv * u[4] + v[4])) : (f16)0.f;
  }
}

// ---------- transition: recompute score dots with decoder att_w ----------
__global__ __launch_bounds__(256) void k_trans(const f16* __restrict__ hxh,
                                               const float* __restrict__ daw,
                                               float* __restrict__ D) {
  int p = blockIdx.x, b = blockIdx.y, q = blockIdx.z, tid = threadIdx.x;
  const f16* h = hxh + ((size_t)p * BB + b) * NN * DD;
  int base = q * 14128;
  float s = 0.f;
  for (int i = base + tid; i < base + 14128; i += 256) s += (float)h[i] * daw[i];
  __shared__ float red[256];
  red[tid] = s; __syncthreads();
  for (int st = 128; st; st >>= 1) { if (tid < st) red[tid] += red[tid + st]; __syncthreads(); }
  if (tid == 0) atomicAdd(&D[(12 + p) * 32 + b], red[0]);
}

// ---------- K1: main diffusion GEMM, K-split x2, 448 blocks ----------
__global__ __launch_bounds__(256, 2) void k_gemm(
    const f16* __restrict__ Sbig, const f16* __restrict__ zin,
    f16* __restrict__ bdh) {
  __shared__ __align__(16) char smem[49152];   // sA dbuf 2x16KB | sB dbuf 2x8KB
  char* sAc = smem;
  char* sBc = smem + 32768;
  int flat = blockIdx.x;
  int xcd = flat & 7, j = flat >> 3;
  int G = xcd * 56 + j;                         // b-major XCD grouping (bijective)
  int b = G / 14, rem = G % 14;
  int kc = rem / 7, br = (rem % 7) * 128;
  const int kbase = kc * 1792;
  int tid = threadIdx.x, lane = tid & 63, w = tid >> 6;
  int l15 = lane & 15, l16 = lane >> 4, x7 = l15 & 7;
  int wr = (w >> 1) * 64, wc = (w & 1) * 32;
  int srow = lane >> 3;
  int sslot = (lane & 7) ^ (srow & 7);          // pre-swizzled source slot

  auto STAGE = [&](int it, int buf) {
    const f16* gA = Sbig + (size_t)br * KBIG + kbase + it * 64;
    #pragma unroll
    for (int o = 0; o < 4; o++) {
      int rg = (w * 4 + o) * 8;
      GLL16(gA + (size_t)(rg + srow) * KBIG + sslot * 8, sAc + buf * 16384 + rg * 128);
    }
    const f16* gB = zin + (size_t)(b * 64) * KBIG + kbase + it * 64;
    #pragma unroll
    for (int o = 0; o < 2; o++) {
      int rg = (w * 2 + o) * 8;
      GLL16(gB + (size_t)(rg + srow) * KBIG + sslot * 8, sBc + buf * 8192 + rg * 128);
    }
  };

  f32x4 acc[4][2] = {};
  STAGE(0, 0);
  for (int it = 0; it < 28; ++it) {
    int cur = it & 1;
    if (it + 1 < 28) {
      STAGE(it + 1, cur ^ 1);
      asm volatile("s_waitcnt vmcnt(6)" ::: "memory");
    } else {
      asm volatile("s_waitcnt vmcnt(0)" ::: "memory");
    }
    __builtin_amdgcn_s_barrier();
    #pragma unroll
    for (int kk = 0; kk < 2; kk++) {
      int q = kk * 4 + l16;
      f16x8 af[4], bf[2];
      #pragma unroll
      for (int fr = 0; fr < 4; fr++) {
        int row = wr + fr * 16 + l15;
        af[fr] = *(const f16x8*)(sAc + cur * 16384 + row * 128 + ((q ^ x7) << 4));
      }
      #pragma unroll
      for (int fc = 0; fc < 2; fc++) {
        int row = wc + fc * 16 + l15;
        bf[fc] = *(const f16x8*)(sBc + cur * 8192 + row * 128 + ((q ^ x7) << 4));
      }
      #pragma unroll
      for (int fr = 0; fr < 4; fr++)
        #pragma unroll
        for (int fc = 0; fc < 2; fc++)
          acc[fr][fc] = __builtin_amdgcn_mfma_f32_16x16x32_f16(af[fr], bf[fc], acc[fr][fc], 0, 0, 0);
    }
    __builtin_amdgcn_s_barrier();
  }
  f16* out = bdh + (size_t)kc * ((size_t)2048 * NP);
  #pragma unroll
  for (int fr = 0; fr < 4; fr++)
    #pragma unroll
    for (int fc = 0; fc < 2; fc++) {
      int n = br + wr + fr * 16 + l16 * 4;
      int d = wc + fc * 16 + l15;
      f16x4 hv;
      #pragma unroll
      for (int r = 0; r < 4; r++) hv[r] = (f16)acc[fr][fc][r];
      *(f16x4*)&out[(size_t)(b * 64 + d) * NP + n] = hv;
    }
}

// ---------- K2: cell finish + fused z-GEMM for t+1, 896 blocks (32-node tiles) ----------
__global__ __launch_bounds__(256, 4) void k_fin(
    int t, int phase, int zmode,
    const f16* __restrict__ bdh, const f16* __restrict__ wfin,
    const float* __restrict__ gb,
    float* __restrict__ D, const float* __restrict__ rdot,
    f16* __restrict__ hxh, float* __restrict__ prevf,
    const float* __restrict__ R, const float* __restrict__ aW,
    const f16* __restrict__ eo_in, f16* __restrict__ eo_out,
    const f16* __restrict__ W2t, const float* __restrict__ uv,
    const float* __restrict__ hist,
    f16* __restrict__ zout, f16* __restrict__ wfout,
    float* __restrict__ dout, const float* __restrict__ pw, const float* __restrict__ pb) {
  __shared__ float lsf[32 * 64];   // conv-pre, transposed+swizzled
  __shared__ f16 ls2h[32 * 64];    // outp f16, swizzled for z-GEMM A-frags
  int flat = blockIdx.x;
  int xcd = flat & 7, jj = flat >> 3;
  int G = xcd * 112 + jj;          // 896 = 8*112, bijective
  int b = G / 28, nt = G % 28;
  int n0 = nt * 32, c0 = b * 64;
  int tid = threadIdx.x, lane = tid & 63, w = tid >> 6;
  int l15 = lane & 15, l16 = lane >> 4, x7 = l15 & 7;

  // softmax weights (redundant per thread)
  float wk[6];
  {
    float sc[6], mx = -1e30f;
    #pragma unroll
    for (int k = 0; k < 6; k++) { sc[k] = D[(t + k) * 32 + b] + rdot[phase * 6 + k]; mx = fmaxf(mx, sc[k]); }
    float se = 0.f;
    #pragma unroll
    for (int k = 0; k < 6; k++) { sc[k] = __expf(sc[k] - mx); se += sc[k]; }
    float inv = 1.f / se;
    #pragma unroll
    for (int k = 0; k < 6; k++) wk[k] = sc[k] * inv;
  }

  // phase A: conv-pre = bd0+bd1+wf+gb, transpose into lsf
  {
    int col = tid >> 2, ns = tid & 3;
    size_t base = (size_t)(c0 + col) * NP + n0 + ns * 8;
    f16x8 p0 = *(const f16x8*)&bdh[base];
    f16x8 p1 = *(const f16x8*)&bdh[(size_t)2048 * NP + base];
    f16x8 wv = *(const f16x8*)&wfin[base];
    float gbv = gb[col];
    #pragma unroll
    for (int jx = 0; jx < 8; jx++) {
      float s = (float)p0[jx] + (float)p1[jx] + (float)wv[jx] + gbv;
      int n_ = ns * 8 + jx;
      lsf[n_ * 64 + (col ^ (n_ & 7))] = s;
    }
  }
  __syncthreads();

  // phase B: cell finish
  int slotW = t % 6;
  const size_t plane = (size_t)BB * NN * DD;
  float pbv = pb[0];
  float dsum = 0.f;
  for (int i = 0; i < 8; i++) {
    int n_l = w + 4 * i;
    int n = n0 + n_l;
    int d = lane;
    float conv = lsf[n_l * 64 + (d ^ (n_l & 7))];
    conv = conv > 0.f ? conv : 0.01f * conv;
    float outp = 0.f;
    if (n < NN) {
      size_t hbase = ((size_t)b * NN + n) * DD + d;
      size_t rbase = (size_t)n * DD + d;
      float att = 0.f;
      #pragma unroll
      for (int k = 0; k < 5; k++) {
        float hv = (t + k >= 6) ? (float)hxh[(size_t)((t + k) % 6) * plane + hbase] : 0.f;
        att += wk[k] * (hv + R[(size_t)k * NN * DD + rbase]);
      }
      float hv5 = (t >= 1) ? prevf[hbase] : 0.f;
      float s5 = hv5 + R[(size_t)5 * NN * DD + rbase];
      att += wk[5] * s5;
      outp = s5 + conv;
      prevf[hbase] = outp;
      hxh[(size_t)slotW * plane + hbase] = (f16)outp;
      float oc = outp + att;
      dsum += outp * aW[rbase];
      if (!phase) {
        eo_out[((size_t)b * NP + n) * DD + d] = (f16)oc;
      } else {
        float pv = oc * pw[d];
        #pragma unroll
        for (int s = 32; s; s >>= 1) pv += __shfl_xor(pv, s);
        if (lane == 0) dout[((size_t)b * HH + (t - LL)) * NN + n] = pv + pbv;
      }
    }
    ls2h[n_l * 64 + (((d >> 3) ^ (n_l & 7)) << 3) + (d & 7)] = (f16)outp;
  }
  #pragma unroll
  for (int s = 32; s; s >>= 1) dsum += __shfl_xor(dsum, s);
  if (lane == 0) atomicAdd(&D[(6 + t) * 32 + b], dsum);
  __syncthreads();

  // phase C: z-GEMM for step t+1 (warp w: A-strip w&1, fb-pair w>>1)
  if (zmode) {
    const int ZKW = (zmode == 2) ? 128 : 64;
    const int kh32 = (zmode == 2) ? 2 : 0;
    int fa = w & 1, fbs = (w >> 1) * 2;
    f16x8 afh[2];
    #pragma unroll
    for (int kk = 0; kk < 2; kk++) {
      int row = fa * 16 + l15;
      afh[kk] = *(const f16x8*)&ls2h[row * 64 + (((kk * 4 + l16) ^ x7) << 3)];
    }
    f16x8 afe[2];
    if (zmode == 2) {
      #pragma unroll
      for (int kk = 0; kk < 2; kk++)
        afe[kk] = *(const f16x8*)&eo_in[((size_t)b * NP + n0 + fa * 16 + l15) * 64 + kk * 32 + l16 * 8];
    }
    float hv_[4];
    if (zmode == 1) {
      #pragma unroll
      for (int r = 0; r < 4; r++) {
        int n = n0 + fa * 16 + l16 * 4 + r;
        hv_[r] = (n < NN) ? hist[((size_t)b * LL + (t + 1)) * NN + n] : 0.f;
      }
    }
    f32x4 wacc[2];
    #pragma unroll
    for (int m = 0; m < 5; m++) {
      f32x4 zacc[2] = {};
      #pragma unroll
      for (int kk = 0; kk < 2; kk++)
        #pragma unroll
        for (int fbi = 0; fbi < 2; fbi++) {
          f16x8 bfv = *(const f16x8*)&W2t[(size_t)(m * 64 + (fbs + fbi) * 16 + l15) * ZKW + (kh32 + kk) * 32 + l16 * 8];
          zacc[fbi] = __builtin_amdgcn_mfma_f32_16x16x32_f16(afh[kk], bfv, zacc[fbi], 0, 0, 0);
        }
      if (zmode == 2) {
        #pragma unroll
        for (int kk = 0; kk < 2; kk++)
          #pragma unroll
          for (int fbi = 0; fbi < 2; fbi++) {
            f16x8 bfv = *(const f16x8*)&W2t[(size_t)(m * 64 + (fbs + fbi) * 16 + l15) * ZKW + kk * 32 + l16 * 8];
            zacc[fbi] = __builtin_amdgcn_mfma_f32_16x16x32_f16(afe[kk], bfv, zacc[fbi], 0, 0, 0);
          }
      }
      if (zmode == 1) {
        #pragma unroll
        for (int fbi = 0; fbi < 2; fbi++) {
          float u = uv[m * 64 + (fbs + fbi) * 16 + l15];
          float v = uv[320 + m * 64 + (fbs + fbi) * 16 + l15];
          #pragma unroll
          for (int r = 0; r < 4; r++) zacc[fbi][r] += hv_[r] * u + v;
        }
      }
      if (m == 0) {
        wacc[0] = zacc[0]; wacc[1] = zacc[1];
      } else {
        if (m == 2 || m == 4) {
          #pragma unroll
          for (int fbi = 0; fbi < 2; fbi++)
            #pragma unroll
            for (int r = 0; r < 4; r++) wacc[fbi][r] -= zacc[fbi][r];
        }
        #pragma unroll
        for (int fbi = 0; fbi < 2; fbi++) {
          int n = n0 + fa * 16 + l16 * 4;
          int d = (fbs + fbi) * 16 + l15;
          f16x4 hv4;
          #pragma unroll
          for (int r = 0; r < 4; r++) hv4[r] = (f16)zacc[fbi][r];
          *(f16x4*)&zout[(size_t)(c0 + d) * KBIG + (m - 1) * NP + n] = hv4;
        }
      }
    }
    #pragma unroll
    for (int fbi = 0; fbi < 2; fbi++) {
      int n = n0 + fa * 16 + l16 * 4;
      int d = (fbs + fbi) * 16 + l15;
      f16x4 wv4;
      #pragma unroll
      for (int r = 0; r < 4; r++) wv4[r] = (f16)wacc[fbi][r];
      *(f16x4*)&wfout[(size_t)(c0 + d) * NP + n] = wv4;
    }
  }
}

// ---------------- host ----------------
extern "C" void kernel_launch(void* const* d_in, const int* in_sizes, int n_in,
                              void* d_out, int out_size, void* d_ws, size_t ws_size,
                              hipStream_t stream) {
  (void)in_sizes; (void)n_in; (void)out_size; (void)ws_size;
  const float* hist = (const float*)d_in[0];
  const float* adj  = (const float*)d_in[1];
  const float* emw  = (const float*)d_in[2];
  const float* emb  = (const float*)d_in[3];
  const float* egw  = (const float*)d_in[4];
  const float* egb  = (const float*)d_in[5];
  const float* eR   = (const float*)d_in[6];
  const float* eaw  = (const float*)d_in[7];
  const float* dgw  = (const float*)d_in[9];
  const float* dgb  = (const float*)d_in[10];
  const float* dR   = (const float*)d_in[11];
  const float* daw  = (const float*)d_in[12];
  const float* pw   = (const float*)d_in[14];
  const float* pb   = (const float*)d_in[15];

  char* wsp = (char*)d_ws;
  size_t off = 0;
  auto take = [&](size_t bytes) { char* p = wsp + off; off = (off + bytes + 255) & ~(size_t)255; return p; };
  f16*   Sbig  = (f16*)  take((size_t)NP * KBIG * 2);
  f16*   S1T   = (f16*)  take((size_t)NP * NP * 2);
  f16*   S2T   = (f16*)  take((size_t)NP * NP * 2);
  float* invr  = (float*)take(NP * 4);
  float* invc  = (float*)take(NP * 4);
  f16*   W2te  = (f16*)  take(5 * 64 * 64 * 2);
  f16*   W2td  = (f16*)  take(5 * 64 * 128 * 2);
  float* uv    = (float*)take(640 * 4);
  float* rdot  = (float*)take(256);
  float* D     = (float*)take(30 * 32 * 4);
  f16*   hxh   = (f16*)  take(6ULL * BB * NN * DD * 2);
  float* prevf = (float*)take((size_t)BB * NN * DD * 4);
  f16*   eoh   = (f16*)  take(12ULL * ZSL * 2);
  f16*   zc0   = (f16*)  take(2048ULL * KBIG * 2);
  f16*   zc1   = (f16*)  take(2048ULL * KBIG * 2);
  f16*   wfh0  = (f16*)  take(2048ULL * NP * 2);
  f16*   wfh1  = (f16*)  take(2048ULL * NP * 2);
  f16*   bdh   = (f16*)  take(2ULL * 2048 * NP * 2);

  hipMemsetAsync(D, 0, 30 * 32 * 4, stream);
  hipMemsetAsync(rdot, 0, 256, stream);

  k_sums<<<dim3(235), 256, 0, stream>>>(adj, invr, invc);
  k_sprep2<<<dim3(14, 14), 256, 0, stream>>>(adj, invr, invc, Sbig, S1T, S2T);
  k_ssq<<<dim3(7, 7, 2), 256, 0, stream>>>(Sbig, S1T, S2T);
  k_wprep<<<dim3(337), 256, 0, stream>>>(egw, dgw, emw, emb, eR, dR, eaw, daw, W2te, W2td, uv, rdot);
  k_z0<<<dim3(2048), 256, 0, stream>>>(hist, uv, zc0, wfh0);

  f16* zc[2] = {zc0, zc1};
  f16* wf[2] = {wfh0, wfh1};
  for (int t = 0; t < 24; t++) {
    int ph = (t >= 12) ? 1 : 0;
    int zmode = (t == 23) ? 0 : ((t + 1 >= 12) ? 2 : 1);
    k_gemm<<<dim3(448), 256, 0, stream>>>(Sbig, zc[t & 1], bdh);
    if (t == 12) {
      hipMemsetAsync((char*)(D + 12 * 32), 0, 6 * 32 * 4, stream);
      k_trans<<<dim3(6, 32, 4), 256, 0, stream>>>(hxh, daw, D);
    }
    k_fin<<<dim3(896), 256, 0, stream>>>(
        t, ph, zmode, bdh, wf[t & 1], ph ? dgb : egb,
        D, rdot, hxh, prevf, ph ? dR : eR, ph ? daw : eaw,
        (zmode == 2) ? (eoh + (size_t)(t + 1 - 12) * ZSL) : eoh,
        ph ? eoh : (eoh + (size_t)t * ZSL),
        (t + 1 < 12) ? W2te : W2td, uv, hist,
        zc[(t + 1) & 1], wf[(t + 1) & 1], (float*)d_out, pw, pb);
  }
}

// Round 7
// 1395.723 us; speedup vs baseline: 1.5228x; 1.5228x over previous
//
#include <hip/hip_runtime.h>
#include <hip/hip_fp16.h>

#define NN 883
#define NP 896
#define DD 64
#define BB 32
#define LL 12
#define HH 12
#define MM 5
#define KBIG 3584          // 4*NP
#define ZSL (32*896*64)    // eoh slice elems

typedef _Float16 f16;
typedef _Float16 f16x4 __attribute__((ext_vector_type(4)));
typedef _Float16 f16x8 __attribute__((ext_vector_type(8)));
typedef float    f32x4 __attribute__((ext_vector_type(4)));

#define GLL16(G, L) __builtin_amdgcn_global_load_lds((const __attribute__((address_space(1))) void*)(G), (__attribute__((address_space(3))) void*)(L), 16, 0, 0)

// ---------- prep: row/col inverse sums ----------
__global__ __launch_bounds__(256) void k_sums(const float* __restrict__ A,
                                              float* __restrict__ invr,
                                              float* __restrict__ invc) {
  int bx = blockIdx.x, tid = threadIdx.x, lane = tid & 63, w = tid >> 6;
  if (bx < 221) {
    int row = bx * 4 + w;
    float s = 0.f;
    if (row < NN) for (int i = lane; i < NN; i += 64) s += A[(size_t)row * NN + i];
    #pragma unroll
    for (int st = 32; st; st >>= 1) s += __shfl_xor(s, st);
    if (lane == 0 && row < NN) invr[row] = 1.0f / s;
  } else {
    int cb = (bx - 221) * 64; int c = cb + lane; int g = w;
    float s = 0.f;
    if (c < NN) for (int r = g; r < NN; r += 4) s += A[(size_t)r * NN + c];
    __shared__ float red2[4][64];
    red2[g][lane] = s; __syncthreads();
    if (tid < 64 && (cb + tid) < NN)
      invc[cb + tid] = 1.0f / (red2[0][tid] + red2[1][tid] + red2[2][tid] + red2[3][tid]);
  }
}

// ---------- prep: Sbig blocks 0,2 + S1T,S2T ----------
__global__ __launch_bounds__(256) void k_sprep2(const float* __restrict__ A,
                                                const float* __restrict__ invr,
                                                const float* __restrict__ invc,
                                                f16* __restrict__ Sbig,
                                                f16* __restrict__ S1T,
                                                f16* __restrict__ S2T) {
  int r0 = blockIdx.y * 64, c0 = blockIdx.x * 64;
  int tid = threadIdx.x, lane = tid & 63, g = tid >> 6;
  __shared__ float tl[64][65];
  for (int i = g; i < 64; i += 4) {
    int r = r0 + i, c = c0 + lane;
    tl[i][lane] = (r < NN && c < NN) ? A[(size_t)r * NN + c] : 0.f;
  }
  __syncthreads();
  for (int i = g; i < 64; i += 4) {
    float v = tl[i][lane];
    int r = r0 + i, c = c0 + lane;
    Sbig[(size_t)r * KBIG + 2 * NP + c] = (f16)(v * invc[c]);   // S2[m=r][k=c]
    S1T[(size_t)r * NP + c] = (f16)(v * invr[r]);
  }
  for (int i = g; i < 64; i += 4) {
    float v = tl[lane][i];                                      // = A[r0+lane][c0+i]
    int m = c0 + i, k = r0 + lane;
    Sbig[(size_t)m * KBIG + k] = (f16)(v * invr[k]);            // S1
    S2T[(size_t)m * NP + k] = (f16)(v * invc[m]);
  }
}

// ---------- prep: Sbig blocks 1,3 = 2*S^2 ----------
__global__ __launch_bounds__(256) void k_ssq(f16* __restrict__ Sbig,
                                             const f16* __restrict__ S1T,
                                             const f16* __restrict__ S2T) {
  int c = blockIdx.z;
  const f16* Bt = c ? S2T : S1T;
  size_t aOff = (size_t)c * 2 * NP;
  int br = blockIdx.x * 128, c0 = blockIdx.y * 128;
  int tid = threadIdx.x;
  __shared__ f16 lA[128 * 32], lB[128 * 32];
  int lane = tid & 63, w = tid >> 6;
  int wr = (w >> 1) * 64, wc = (w & 1) * 64;
  int l15 = lane & 15, k8 = (lane >> 4) * 8;
  f32x4 acc[4][4] = {};
  for (int ks = 0; ks < NP; ks += 32) {
    __syncthreads();
    #pragma unroll
    for (int j = 0; j < 2; j++) {
      int idx = tid + j * 256;
      int row = idx >> 2, c8 = idx & 3;
      *(f16x8*)&lA[row * 32 + c8 * 8] = *(const f16x8*)(Sbig + (size_t)(br + row) * KBIG + aOff + ks + c8 * 8);
      *(f16x8*)&lB[row * 32 + c8 * 8] = *(const f16x8*)(Bt + (size_t)(c0 + row) * NP + ks + c8 * 8);
    }
    __syncthreads();
    f16x8 af[4], bf[4];
    #pragma unroll
    for (int fr = 0; fr < 4; fr++) af[fr] = *(const f16x8*)&lA[(wr + fr * 16 + l15) * 32 + k8];
    #pragma unroll
    for (int fc = 0; fc < 4; fc++) bf[fc] = *(const f16x8*)&lB[(wc + fc * 16 + l15) * 32 + k8];
    #pragma unroll
    for (int fr = 0; fr < 4; fr++)
      #pragma unroll
      for (int fc = 0; fc < 4; fc++)
        acc[fr][fc] = __builtin_amdgcn_mfma_f32_16x16x32_f16(af[fr], bf[fc], acc[fr][fc], 0, 0, 0);
  }
  size_t cOff = (size_t)(2 * c + 1) * NP;
  #pragma unroll
  for (int fr = 0; fr < 4; fr++)
    #pragma unroll
    for (int fc = 0; fc < 4; fc++) {
      int mmb = br + wr + fr * 16 + (lane >> 4) * 4;
      int ncol = c0 + wc + fc * 16 + l15;
      #pragma unroll
      for (int r = 0; r < 4; r++)
        Sbig[(size_t)(mmb + r) * KBIG + cOff + ncol] = (f16)(2.0f * acc[fr][fc][r]);
    }
}

// ---------- prep: W reorg + rank1 + rdot + Rh/awh f16 copies ----------
__global__ __launch_bounds__(256) void k_wprep(
    const float* __restrict__ egw, const float* __restrict__ dgw,
    const float* __restrict__ emw, const float* __restrict__ emb,
    const float* __restrict__ eR,  const float* __restrict__ dR,
    const float* __restrict__ eaw, const float* __restrict__ daw,
    f16* __restrict__ W2te, f16* __restrict__ W2td,
    float* __restrict__ uv, float* __restrict__ rdot,
    f16* __restrict__ Rh, f16* __restrict__ awh) {
  int bx = blockIdx.x, tid = threadIdx.x;
  if (bx < 96) {
    int ph = bx / 48, k = (bx / 8) % 6, part = bx & 7;
    const float* R  = ph ? dR : eR;
    const float* aw = ph ? daw : eaw;
    const float* Rk = R + (size_t)k * NN * DD;
    int base = part * 7064;
    float s = 0.f;
    for (int i = base + tid; i < base + 7064; i += 256) s += Rk[i] * aw[i];
    __shared__ float red[256];
    red[tid] = s; __syncthreads();
    for (int st = 128; st; st >>= 1) { if (tid < st) red[tid] += red[tid + st]; __syncthreads(); }
    if (tid == 0) atomicAdd(&rdot[ph * 6 + k], red[0]);
  } else if (bx == 96) {
    __shared__ float ru[4][64], rv[4][64];
    int g = tid >> 6, d = tid & 63;
    for (int m = 0; m < 5; m++) {
      float u = 0.f, v = 0.f;
      for (int f = g; f < 64; f += 4) {
        float w = egw[(size_t)(f * MM + m) * DD + d];
        u += emw[f] * w;
        v += emb[f] * w;
      }
      ru[g][d] = u; rv[g][d] = v; __syncthreads();
      if (tid < 64) {
        uv[m * 64 + tid] = ru[0][tid] + ru[1][tid] + ru[2][tid] + ru[3][tid];
        uv[320 + m * 64 + tid] = rv[0][tid] + rv[1][tid] + rv[2][tid] + rv[3][tid];
      }
      __syncthreads();
    }
  } else if (bx < 177) {
    int idx = (bx - 97) * 256 + tid;            // W2te[m][d][kf], f=64+kf
    int m = idx >> 12, d = (idx >> 6) & 63, kf = idx & 63;
    W2te[idx] = (f16)egw[(size_t)((64 + kf) * MM + m) * DD + d];
  } else if (bx < 337) {
    int idx = (bx - 177) * 256 + tid;           // W2td[m][d][kf], f=kf
    int m = idx >> 13, d = (idx >> 7) & 63, kf = idx & 127;
    W2td[idx] = (f16)dgw[(size_t)(kf * MM + m) * DD + d];
  } else if (bx < 2986) {
    int idx = (bx - 337) * 256 + tid;           // Rh[ph][k][n][d]
    int ph = idx / (6 * NN * DD);
    int rem = idx - ph * (6 * NN * DD);
    Rh[idx] = (f16)((ph ? dR : eR)[rem]);
  } else {
    int idx = (bx - 2986) * 256 + tid;          // awh[ph][n][d]
    if (idx < 2 * NN * DD) {
      int ph = idx / (NN * DD);
      int rem = idx - ph * (NN * DD);
      awh[idx] = (f16)((ph ? daw : eaw)[rem]);
    }
  }
}

// ---------- init: zcat(0), wf(0) ----------
__global__ __launch_bounds__(256) void k_z0(const float* __restrict__ hist,
                                            const float* __restrict__ uv,
                                            f16* __restrict__ zout,
                                            f16* __restrict__ wfout) {
  int col = blockIdx.x;               // b*64+d
  int b = col >> 6, d = col & 63;
  float u[5], v[5];
  #pragma unroll
  for (int m = 0; m < 5; m++) { u[m] = uv[m * 64 + d]; v[m] = uv[320 + m * 64 + d]; }
  for (int n = threadIdx.x; n < NP; n += 256) {
    bool valid = n < NN;
    float hv = valid ? hist[(size_t)b * LL * NN + n] : 0.f;
    #pragma unroll
    for (int m = 1; m < 5; m++)
      zout[(size_t)col * KBIG + (m - 1) * NP + n] = valid ? (f16)(hv * u[m] + v[m]) : (f16)0.f;
    wfout[(size_t)col * NP + n] = valid ?
      (f16)((hv * u[0] + v[0]) - (hv * u[2] + v[2]) - (hv * u[4] + v[4])) : (f16)0.f;
  }
}

// ---------- transition: recompute score dots with decoder att_w ----------
__global__ __launch_bounds__(256) void k_trans(const f16* __restrict__ hxh,
                                               const float* __restrict__ daw,
                                               float* __restrict__ D) {
  int p = blockIdx.x, b = blockIdx.y, q = blockIdx.z, tid = threadIdx.x;
  const f16* h = hxh + ((size_t)p * BB + b) * NN * DD;
  int base = q * 14128;
  float s = 0.f;
  for (int i = base + tid; i < base + 14128; i += 256) s += (float)h[i] * daw[i];
  __shared__ float red[256];
  red[tid] = s; __syncthreads();
  for (int st = 128; st; st >>= 1) { if (tid < st) red[tid] += red[tid + st]; __syncthreads(); }
  if (tid == 0) atomicAdd(&D[(12 + p) * 32 + b], red[0]);
}

// ---------- K1: main diffusion GEMM, K-split x2, 448 blocks ----------
__global__ __launch_bounds__(256, 2) void k_gemm(
    const f16* __restrict__ Sbig, const f16* __restrict__ zin,
    f16* __restrict__ bdh) {
  __shared__ __align__(16) char smem[49152];   // sA dbuf 2x16KB | sB dbuf 2x8KB
  char* sAc = smem;
  char* sBc = smem + 32768;
  int flat = blockIdx.x;
  int xcd = flat & 7, j = flat >> 3;
  int G = xcd * 56 + j;                         // b-major XCD grouping (bijective)
  int b = G / 14, rem = G % 14;
  int kc = rem / 7, br = (rem % 7) * 128;
  const int kbase = kc * 1792;
  int tid = threadIdx.x, lane = tid & 63, w = tid >> 6;
  int l15 = lane & 15, l16 = lane >> 4, x7 = l15 & 7;
  int wr = (w >> 1) * 64, wc = (w & 1) * 32;
  int srow = lane >> 3;
  int sslot = (lane & 7) ^ (srow & 7);          // pre-swizzled source slot

  auto STAGE = [&](int it, int buf) {
    const f16* gA = Sbig + (size_t)br * KBIG + kbase + it * 64;
    #pragma unroll
    for (int o = 0; o < 4; o++) {
      int rg = (w * 4 + o) * 8;
      GLL16(gA + (size_t)(rg + srow) * KBIG + sslot * 8, sAc + buf * 16384 + rg * 128);
    }
    const f16* gB = zin + (size_t)(b * 64) * KBIG + kbase + it * 64;
    #pragma unroll
    for (int o = 0; o < 2; o++) {
      int rg = (w * 2 + o) * 8;
      GLL16(gB + (size_t)(rg + srow) * KBIG + sslot * 8, sBc + buf * 8192 + rg * 128);
    }
  };

  f32x4 acc[4][2] = {};
  STAGE(0, 0);
  for (int it = 0; it < 28; ++it) {
    int cur = it & 1;
    if (it + 1 < 28) {
      STAGE(it + 1, cur ^ 1);
      asm volatile("s_waitcnt vmcnt(6)" ::: "memory");
    } else {
      asm volatile("s_waitcnt vmcnt(0)" ::: "memory");
    }
    __builtin_amdgcn_s_barrier();
    #pragma unroll
    for (int kk = 0; kk < 2; kk++) {
      int q = kk * 4 + l16;
      f16x8 af[4], bf[2];
      #pragma unroll
      for (int fr = 0; fr < 4; fr++) {
        int row = wr + fr * 16 + l15;
        af[fr] = *(const f16x8*)(sAc + cur * 16384 + row * 128 + ((q ^ x7) << 4));
      }
      #pragma unroll
      for (int fc = 0; fc < 2; fc++) {
        int row = wc + fc * 16 + l15;
        bf[fc] = *(const f16x8*)(sBc + cur * 8192 + row * 128 + ((q ^ x7) << 4));
      }
      #pragma unroll
      for (int fr = 0; fr < 4; fr++)
        #pragma unroll
        for (int fc = 0; fc < 2; fc++)
          acc[fr][fc] = __builtin_amdgcn_mfma_f32_16x16x32_f16(af[fr], bf[fc], acc[fr][fc], 0, 0, 0);
    }
    __builtin_amdgcn_s_barrier();
  }
  f16* out = bdh + (size_t)kc * ((size_t)2048 * NP);
  #pragma unroll
  for (int fr = 0; fr < 4; fr++)
    #pragma unroll
    for (int fc = 0; fc < 2; fc++) {
      int n = br + wr + fr * 16 + l16 * 4;
      int d = wc + fc * 16 + l15;
      f16x4 hv;
      #pragma unroll
      for (int r = 0; r < 4; r++) hv[r] = (f16)acc[fr][fc][r];
      *(f16x4*)&out[(size_t)(b * 64 + d) * NP + n] = hv;
    }
}

// ---------- K2: cell finish + fused z-GEMM for t+1, 896 blocks (32-node tiles) ----------
__global__ __launch_bounds__(256, 4) void k_fin(
    int t, int phase, int zmode,
    const f16* __restrict__ bdh, const f16* __restrict__ wfin,
    const float* __restrict__ gb,
    float* __restrict__ D, const float* __restrict__ rdot,
    f16* __restrict__ hxh, float* __restrict__ prevf,
    const f16* __restrict__ Rh, const f16* __restrict__ awh,
    const f16* __restrict__ eo_in, f16* __restrict__ eo_out,
    const f16* __restrict__ W2t, const float* __restrict__ uv,
    const float* __restrict__ hist,
    f16* __restrict__ zout, f16* __restrict__ wfout,
    float* __restrict__ dout, const float* __restrict__ pw, const float* __restrict__ pb) {
  __shared__ float lsf[32 * 64];   // conv-pre, transposed+swizzled
  __shared__ f16 ls2h[32 * 64];    // outp f16, swizzled for z-GEMM A-frags
  __shared__ float redw[4];
  int flat = blockIdx.x;
  int xcd = flat & 7, jj = flat >> 3;
  int G = xcd * 112 + jj;          // 896 = 8*112, bijective
  int b = G / 28, nt = G % 28;
  int n0 = nt * 32, c0 = b * 64;
  int tid = threadIdx.x, lane = tid & 63, w = tid >> 6;
  int l15 = lane & 15, l16 = lane >> 4, x7 = l15 & 7;

  // softmax weights (redundant per thread)
  float wk[6];
  {
    float sc[6], mx = -1e30f;
    #pragma unroll
    for (int k = 0; k < 6; k++) { sc[k] = D[(t + k) * 32 + b] + rdot[phase * 6 + k]; mx = fmaxf(mx, sc[k]); }
    float se = 0.f;
    #pragma unroll
    for (int k = 0; k < 6; k++) { sc[k] = __expf(sc[k] - mx); se += sc[k]; }
    float inv = 1.f / se;
    #pragma unroll
    for (int k = 0; k < 6; k++) wk[k] = sc[k] * inv;
  }

  // phase A: conv-pre = bd0+bd1+wf+gb, transpose into lsf
  {
    int col = tid >> 2, ns = tid & 3;
    size_t base = (size_t)(c0 + col) * NP + n0 + ns * 8;
    f16x8 p0 = *(const f16x8*)&bdh[base];
    f16x8 p1 = *(const f16x8*)&bdh[(size_t)2048 * NP + base];
    f16x8 wv = *(const f16x8*)&wfin[base];
    float gbv = gb[col];
    #pragma unroll
    for (int jx = 0; jx < 8; jx++) {
      float s = (float)p0[jx] + (float)p1[jx] + (float)wv[jx] + gbv;
      int n_ = ns * 8 + jx;
      lsf[n_ * 64 + (col ^ (n_ & 7))] = s;
    }
  }
  __syncthreads();

  // phase B: cell finish — thread = (row = tid>>3, d-octet q = tid&7); all wide loads
  int slotW = t % 6;
  const size_t plane = (size_t)BB * NN * DD;
  {
    int row = tid >> 3, q = tid & 7;
    int n = n0 + row, d0 = q * 8;
    bool valid = n < NN;
    size_t hb = ((size_t)b * NN + n) * DD + d0;
    f16x8 zz = {};
    f16x8 hp[5], rk[6], awv;
    f32x4 pv0 = {}, pv1 = {};
    if (valid) {
      #pragma unroll
      for (int k = 0; k < 5; k++)
        hp[k] = (t + k >= 6) ? *(const f16x8*)&hxh[(size_t)((t + k) % 6) * plane + hb] : zz;
      if (t >= 1) { pv0 = *(const f32x4*)&prevf[hb]; pv1 = *(const f32x4*)&prevf[hb + 4]; }
      #pragma unroll
      for (int k = 0; k < 6; k++)
        rk[k] = *(const f16x8*)&Rh[(((size_t)phase * 6 + k) * NN + n) * DD + d0];
      awv = *(const f16x8*)&awh[((size_t)phase * NN + n) * DD + d0];
    } else {
      #pragma unroll
      for (int k = 0; k < 5; k++) hp[k] = zz;
      #pragma unroll
      for (int k = 0; k < 6; k++) rk[k] = zz;
      awv = zz;
    }
    f32x4 pw0 = *(const f32x4*)&pw[d0];
    f32x4 pw1 = *(const f32x4*)&pw[d0 + 4];
    float dsum = 0.f, psum = 0.f;
    f16x8 houtv = zz, eov = zz;
    f32x4 np0 = {}, np1 = {};
    #pragma unroll
    for (int jx = 0; jx < 8; jx++) {
      int d = d0 + jx;
      float conv = lsf[row * 64 + (d ^ (row & 7))];
      conv = conv > 0.f ? conv : 0.01f * conv;
      float prev = (jx < 4) ? pv0[jx & 3] : pv1[jx & 3];
      float att = 0.f;
      #pragma unroll
      for (int k = 0; k < 5; k++) att += wk[k] * ((float)hp[k][jx] + (float)rk[k][jx]);
      float s5 = prev + (float)rk[5][jx];
      att += wk[5] * s5;
      float outp = s5 + conv;
      if (jx < 4) np0[jx & 3] = outp; else np1[jx & 3] = outp;
      houtv[jx] = (f16)outp;
      float oc = outp + att;
      dsum += outp * (float)awv[jx];
      if (!phase) eov[jx] = (f16)oc;
      else psum += oc * ((jx < 4) ? pw0[jx & 3] : pw1[jx & 3]);
    }
    if (valid) {
      *(f16x8*)&hxh[(size_t)slotW * plane + hb] = houtv;
      *(f32x4*)&prevf[hb] = np0;
      *(f32x4*)&prevf[hb + 4] = np1;
      if (!phase) *(f16x8*)&eo_out[((size_t)b * NP + n) * DD + d0] = eov;
    }
    *(f16x8*)&ls2h[row * 64 + ((q ^ (row & 7)) << 3)] = houtv;
    if (phase) {
      psum += __shfl_xor(psum, 1);
      psum += __shfl_xor(psum, 2);
      psum += __shfl_xor(psum, 4);
      if (valid && q == 0) dout[((size_t)b * HH + (t - LL)) * NN + n] = psum + pb[0];
    }
    #pragma unroll
    for (int s = 32; s; s >>= 1) dsum += __shfl_xor(dsum, s);
    if (lane == 0) redw[w] = dsum;
  }
  __syncthreads();
  if (tid == 0) atomicAdd(&D[(6 + t) * 32 + b], redw[0] + redw[1] + redw[2] + redw[3]);

  // phase C: z-GEMM for step t+1 (warp w: A-strip w&1, fb-pair w>>1)
  if (zmode) {
    const int ZKW = (zmode == 2) ? 128 : 64;
    const int kh32 = (zmode == 2) ? 2 : 0;
    int fa = w & 1, fbs = (w >> 1) * 2;
    f16x8 afh[2];
    #pragma unroll
    for (int kk = 0; kk < 2; kk++) {
      int row = fa * 16 + l15;
      afh[kk] = *(const f16x8*)&ls2h[row * 64 + (((kk * 4 + l16) ^ x7) << 3)];
    }
    f16x8 afe[2];
    if (zmode == 2) {
      #pragma unroll
      for (int kk = 0; kk < 2; kk++)
        afe[kk] = *(const f16x8*)&eo_in[((size_t)b * NP + n0 + fa * 16 + l15) * 64 + kk * 32 + l16 * 8];
    }
    float hv_[4];
    if (zmode == 1) {
      #pragma unroll
      for (int r = 0; r < 4; r++) {
        int n = n0 + fa * 16 + l16 * 4 + r;
        hv_[r] = (n < NN) ? hist[((size_t)b * LL + (t + 1)) * NN + n] : 0.f;
      }
    }
    f32x4 wacc[2];
    #pragma unroll
    for (int m = 0; m < 5; m++) {
      f32x4 zacc[2] = {};
      #pragma unroll
      for (int kk = 0; kk < 2; kk++)
        #pragma unroll
        for (int fbi = 0; fbi < 2; fbi++) {
          f16x8 bfv = *(const f16x8*)&W2t[(size_t)(m * 64 + (fbs + fbi) * 16 + l15) * ZKW + (kh32 + kk) * 32 + l16 * 8];
          zacc[fbi] = __builtin_amdgcn_mfma_f32_16x16x32_f16(afh[kk], bfv, zacc[fbi], 0, 0, 0);
        }
      if (zmode == 2) {
        #pragma unroll
        for (int kk = 0; kk < 2; kk++)
          #pragma unroll
          for (int fbi = 0; fbi < 2; fbi++) {
            f16x8 bfv = *(const f16x8*)&W2t[(size_t)(m * 64 + (fbs + fbi) * 16 + l15) * ZKW + kk * 32 + l16 * 8];
            zacc[fbi] = __builtin_amdgcn_mfma_f32_16x16x32_f16(afe[kk], bfv, zacc[fbi], 0, 0, 0);
          }
      }
      if (zmode == 1) {
        #pragma unroll
        for (int fbi = 0; fbi < 2; fbi++) {
          float u = uv[m * 64 + (fbs + fbi) * 16 + l15];
          float v = uv[320 + m * 64 + (fbs + fbi) * 16 + l15];
          #pragma unroll
          for (int r = 0; r < 4; r++) zacc[fbi][r] += hv_[r] * u + v;
        }
      }
      if (m == 0) {
        wacc[0] = zacc[0]; wacc[1] = zacc[1];
      } else {
        if (m == 2 || m == 4) {
          #pragma unroll
          for (int fbi = 0; fbi < 2; fbi++)
            #pragma unroll
            for (int r = 0; r < 4; r++) wacc[fbi][r] -= zacc[fbi][r];
        }
        #pragma unroll
        for (int fbi = 0; fbi < 2; fbi++) {
          int n = n0 + fa * 16 + l16 * 4;
          int d = (fbs + fbi) * 16 + l15;
          f16x4 hv4;
          #pragma unroll
          for (int r = 0; r < 4; r++) hv4[r] = (f16)zacc[fbi][r];
          *(f16x4*)&zout[(size_t)(c0 + d) * KBIG + (m - 1) * NP + n] = hv4;
        }
      }
    }
    #pragma unroll
    for (int fbi = 0; fbi < 2; fbi++) {
      int n = n0 + fa * 16 + l16 * 4;
      int d = (fbs + fbi) * 16 + l15;
      f16x4 wv4;
      #pragma unroll
      for (int r = 0; r < 4; r++) wv4[r] = (f16)wacc[fbi][r];
      *(f16x4*)&wfout[(size_t)(c0 + d) * NP + n] = wv4;
    }
  }
}

// ---------------- host ----------------
extern "C" void kernel_launch(void* const* d_in, const int* in_sizes, int n_in,
                              void* d_out, int out_size, void* d_ws, size_t ws_size,
                              hipStream_t stream) {
  (void)in_sizes; (void)n_in; (void)out_size; (void)ws_size;
  const float* hist = (const float*)d_in[0];
  const float* adj  = (const float*)d_in[1];
  const float* emw  = (const float*)d_in[2];
  const float* emb  = (const float*)d_in[3];
  const float* egw  = (const float*)d_in[4];
  const float* egb  = (const float*)d_in[5];
  const float* eR   = (const float*)d_in[6];
  const float* eaw  = (const float*)d_in[7];
  const float* dgw  = (const float*)d_in[9];
  const float* dgb  = (const float*)d_in[10];
  const float* dR   = (const float*)d_in[11];
  const float* daw  = (const float*)d_in[12];
  const float* pw   = (const float*)d_in[14];
  const float* pb   = (const float*)d_in[15];

  char* wsp = (char*)d_ws;
  size_t off = 0;
  auto take = [&](size_t bytes) { char* p = wsp + off; off = (off + bytes + 255) & ~(size_t)255; return p; };
  f16*   Sbig  = (f16*)  take((size_t)NP * KBIG * 2);
  f16*   S1T   = (f16*)  take((size_t)NP * NP * 2);
  f16*   S2T   = (f16*)  take((size_t)NP * NP * 2);
  float* invr  = (float*)take(NP * 4);
  float* invc  = (float*)take(NP * 4);
  f16*   W2te  = (f16*)  take(5 * 64 * 64 * 2);
  f16*   W2td  = (f16*)  take(5 * 64 * 128 * 2);
  float* uv    = (float*)take(640 * 4);
  float* rdot  = (float*)take(256);
  float* D     = (float*)take(30 * 32 * 4);
  f16*   hxh   = (f16*)  take(6ULL * BB * NN * DD * 2);
  float* prevf = (float*)take((size_t)BB * NN * DD * 4);
  f16*   Rh    = (f16*)  take(2ULL * 6 * NN * DD * 2);
  f16*   awh   = (f16*)  take(2ULL * NN * DD * 2);
  f16*   eoh   = (f16*)  take(12ULL * ZSL * 2);
  f16*   zc0   = (f16*)  take(2048ULL * KBIG * 2);
  f16*   zc1   = (f16*)  take(2048ULL * KBIG * 2);
  f16*   wfh0  = (f16*)  take(2048ULL * NP * 2);
  f16*   wfh1  = (f16*)  take(2048ULL * NP * 2);
  f16*   bdh   = (f16*)  take(2ULL * 2048 * NP * 2);

  hipMemsetAsync(D, 0, 30 * 32 * 4, stream);
  hipMemsetAsync(rdot, 0, 256, stream);

  k_sums<<<dim3(235), 256, 0, stream>>>(adj, invr, invc);
  k_sprep2<<<dim3(14, 14), 256, 0, stream>>>(adj, invr, invc, Sbig, S1T, S2T);
  k_ssq<<<dim3(7, 7, 2), 256, 0, stream>>>(Sbig, S1T, S2T);
  k_wprep<<<dim3(3428), 256, 0, stream>>>(egw, dgw, emw, emb, eR, dR, eaw, daw,
                                          W2te, W2td, uv, rdot, Rh, awh);
  k_z0<<<dim3(2048), 256, 0, stream>>>(hist, uv, zc0, wfh0);

  f16* zc[2] = {zc0, zc1};
  f16* wf[2] = {wfh0, wfh1};
  for (int t = 0; t < 24; t++) {
    int ph = (t >= 12) ? 1 : 0;
    int zmode = (t == 23) ? 0 : ((t + 1 >= 12) ? 2 : 1);
    k_gemm<<<dim3(448), 256, 0, stream>>>(Sbig, zc[t & 1], bdh);
    if (t == 12) {
      hipMemsetAsync((char*)(D + 12 * 32), 0, 6 * 32 * 4, stream);
      k_trans<<<dim3(6, 32, 4), 256, 0, stream>>>(hxh, daw, D);
    }
    k_fin<<<dim3(896), 256, 0, stream>>>(
        t, ph, zmode, bdh, wf[t & 1], ph ? dgb : egb,
        D, rdot, hxh, prevf, Rh, awh,
        (zmode == 2) ? (eoh + (size_t)(t + 1 - 12) * ZSL) : eoh,
        ph ? eoh : (eoh + (size_t)t * ZSL),
        (t + 1 < 12) ? W2te : W2td, uv, hist,
        zc[(t + 1) & 1], wf[(t + 1) & 1], (float*)d_out, pw, pb);
  }
}

// Round 8
// 1347.871 us; speedup vs baseline: 1.5769x; 1.0355x over previous
//
#include <hip/hip_runtime.h>
#include <hip/hip_fp16.h>

#define NN 883
#define NP 896
#define DD 64
#define BB 32
#define LL 12
#define HH 12
#define MM 5
#define KBIG 3584          // 4*NP
#define ZSL (32*896*64)    // eoh slice elems

typedef _Float16 f16;
typedef _Float16 f16x4 __attribute__((ext_vector_type(4)));
typedef _Float16 f16x8 __attribute__((ext_vector_type(8)));
typedef float    f32x4 __attribute__((ext_vector_type(4)));

#define GLL16(G, L) __builtin_amdgcn_global_load_lds((const __attribute__((address_space(1))) void*)(G), (__attribute__((address_space(3))) void*)(L), 16, 0, 0)

// ---------- prep: row inverse sums + parallel col sums (atomic) ----------
__global__ __launch_bounds__(256) void k_sums(const float* __restrict__ A,
                                              float* __restrict__ invr,
                                              float* __restrict__ csum) {
  int bx = blockIdx.x, tid = threadIdx.x, lane = tid & 63, w = tid >> 6;
  if (bx < 221) {
    int row = bx * 4 + w;
    float s = 0.f;
    if (row < NN) for (int i = lane; i < NN; i += 64) s += A[(size_t)row * NN + i];
    #pragma unroll
    for (int st = 32; st; st >>= 1) s += __shfl_xor(s, st);
    if (lane == 0 && row < NN) invr[row] = 1.0f / s;
  } else {
    int idx = bx - 221;                 // 0..223 : 14 col-tiles x 16 row-chunks
    int c0 = (idx % 14) * 64;
    int r0 = (idx / 14) * 56;
    int c = c0 + lane;
    float s = 0.f;
    if (c < NN) {
      int rend = r0 + 56; if (rend > NN) rend = NN;
      for (int r = r0 + w; r < rend; r += 4) s += A[(size_t)r * NN + c];
    }
    __shared__ float red2[4][64];
    red2[w][lane] = s; __syncthreads();
    if (tid < 64 && (c0 + tid) < NN)
      atomicAdd(&csum[c0 + tid], red2[0][tid] + red2[1][tid] + red2[2][tid] + red2[3][tid]);
  }
}

// ---------- prep: Sbig blocks 0,2 + S1T,S2T (col-inverse computed inline) ----------
__global__ __launch_bounds__(256) void k_sprep2(const float* __restrict__ A,
                                                const float* __restrict__ invr,
                                                const float* __restrict__ csum,
                                                f16* __restrict__ Sbig,
                                                f16* __restrict__ S1T,
                                                f16* __restrict__ S2T) {
  int r0 = blockIdx.y * 64, c0 = blockIdx.x * 64;
  int tid = threadIdx.x, lane = tid & 63, g = tid >> 6;
  __shared__ float tl[64][65];
  for (int i = g; i < 64; i += 4) {
    int r = r0 + i, c = c0 + lane;
    tl[i][lane] = (r < NN && c < NN) ? A[(size_t)r * NN + c] : 0.f;
  }
  __syncthreads();
  {
    int c = c0 + lane;
    float icc = (c < NN) ? 1.0f / csum[c] : 0.f;
    for (int i = g; i < 64; i += 4) {
      float v = tl[i][lane];
      int r = r0 + i;
      Sbig[(size_t)r * KBIG + 2 * NP + c] = (f16)(v * icc);     // S2[m=r][k=c]
      S1T[(size_t)r * NP + c] = (f16)(v * invr[r]);
    }
  }
  for (int i = g; i < 64; i += 4) {
    float v = tl[lane][i];                                      // = A[r0+lane][c0+i]
    int m = c0 + i, k = r0 + lane;
    float icm = (m < NN) ? 1.0f / csum[m] : 0.f;
    Sbig[(size_t)m * KBIG + k] = (f16)(v * invr[k]);            // S1
    S2T[(size_t)m * NP + k] = (f16)(v * icm);
  }
}

// ---------- prep: Sbig blocks 1,3 = 2*S^2 ----------
__global__ __launch_bounds__(256) void k_ssq(f16* __restrict__ Sbig,
                                             const f16* __restrict__ S1T,
                                             const f16* __restrict__ S2T) {
  int c = blockIdx.z;
  const f16* Bt = c ? S2T : S1T;
  size_t aOff = (size_t)c * 2 * NP;
  int br = blockIdx.x * 128, c0 = blockIdx.y * 128;
  int tid = threadIdx.x;
  __shared__ f16 lA[128 * 32], lB[128 * 32];
  int lane = tid & 63, w = tid >> 6;
  int wr = (w >> 1) * 64, wc = (w & 1) * 64;
  int l15 = lane & 15, k8 = (lane >> 4) * 8;
  f32x4 acc[4][4] = {};
  for (int ks = 0; ks < NP; ks += 32) {
    __syncthreads();
    #pragma unroll
    for (int j = 0; j < 2; j++) {
      int idx = tid + j * 256;
      int row = idx >> 2, c8 = idx & 3;
      *(f16x8*)&lA[row * 32 + c8 * 8] = *(const f16x8*)(Sbig + (size_t)(br + row) * KBIG + aOff + ks + c8 * 8);
      *(f16x8*)&lB[row * 32 + c8 * 8] = *(const f16x8*)(Bt + (size_t)(c0 + row) * NP + ks + c8 * 8);
    }
    __syncthreads();
    f16x8 af[4], bf[4];
    #pragma unroll
    for (int fr = 0; fr < 4; fr++) af[fr] = *(const f16x8*)&lA[(wr + fr * 16 + l15) * 32 + k8];
    #pragma unroll
    for (int fc = 0; fc < 4; fc++) bf[fc] = *(const f16x8*)&lB[(wc + fc * 16 + l15) * 32 + k8];
    #pragma unroll
    for (int fr = 0; fr < 4; fr++)
      #pragma unroll
      for (int fc = 0; fc < 4; fc++)
        acc[fr][fc] = __builtin_amdgcn_mfma_f32_16x16x32_f16(af[fr], bf[fc], acc[fr][fc], 0, 0, 0);
  }
  size_t cOff = (size_t)(2 * c + 1) * NP;
  #pragma unroll
  for (int fr = 0; fr < 4; fr++)
    #pragma unroll
    for (int fc = 0; fc < 4; fc++) {
      int mmb = br + wr + fr * 16 + (lane >> 4) * 4;
      int ncol = c0 + wc + fc * 16 + l15;
      #pragma unroll
      for (int r = 0; r < 4; r++)
        Sbig[(size_t)(mmb + r) * KBIG + cOff + ncol] = (f16)(2.0f * acc[fr][fc][r]);
    }
}

// ---------- prep: W reorg + rank1 + rdot + Rh/awh f16 copies ----------
__global__ __launch_bounds__(256) void k_wprep(
    const float* __restrict__ egw, const float* __restrict__ dgw,
    const float* __restrict__ emw, const float* __restrict__ emb,
    const float* __restrict__ eR,  const float* __restrict__ dR,
    const float* __restrict__ eaw, const float* __restrict__ daw,
    f16* __restrict__ W2te, f16* __restrict__ W2td,
    float* __restrict__ uv, float* __restrict__ rdot,
    f16* __restrict__ Rh, f16* __restrict__ awh) {
  int bx = blockIdx.x, tid = threadIdx.x;
  if (bx < 96) {
    int ph = bx / 48, k = (bx / 8) % 6, part = bx & 7;
    const float* R  = ph ? dR : eR;
    const float* aw = ph ? daw : eaw;
    const float* Rk = R + (size_t)k * NN * DD;
    int base = part * 7064;
    float s = 0.f;
    for (int i = base + tid; i < base + 7064; i += 256) s += Rk[i] * aw[i];
    __shared__ float red[256];
    red[tid] = s; __syncthreads();
    for (int st = 128; st; st >>= 1) { if (tid < st) red[tid] += red[tid + st]; __syncthreads(); }
    if (tid == 0) atomicAdd(&rdot[ph * 6 + k], red[0]);
  } else if (bx == 96) {
    __shared__ float ru[4][64], rv[4][64];
    int g = tid >> 6, d = tid & 63;
    for (int m = 0; m < 5; m++) {
      float u = 0.f, v = 0.f;
      for (int f = g; f < 64; f += 4) {
        float w = egw[(size_t)(f * MM + m) * DD + d];
        u += emw[f] * w;
        v += emb[f] * w;
      }
      ru[g][d] = u; rv[g][d] = v; __syncthreads();
      if (tid < 64) {
        uv[m * 64 + tid] = ru[0][tid] + ru[1][tid] + ru[2][tid] + ru[3][tid];
        uv[320 + m * 64 + tid] = rv[0][tid] + rv[1][tid] + rv[2][tid] + rv[3][tid];
      }
      __syncthreads();
    }
  } else if (bx < 177) {
    int idx = (bx - 97) * 256 + tid;            // W2te[m][d][kf], f=64+kf
    int m = idx >> 12, d = (idx >> 6) & 63, kf = idx & 63;
    W2te[idx] = (f16)egw[(size_t)((64 + kf) * MM + m) * DD + d];
  } else if (bx < 337) {
    int idx = (bx - 177) * 256 + tid;           // W2td[m][d][kf], f=kf
    int m = idx >> 13, d = (idx >> 7) & 63, kf = idx & 127;
    W2td[idx] = (f16)dgw[(size_t)(kf * MM + m) * DD + d];
  } else if (bx < 2986) {
    int idx = (bx - 337) * 256 + tid;           // Rh[ph][k][n][d]
    int ph = idx / (6 * NN * DD);
    int rem = idx - ph * (6 * NN * DD);
    Rh[idx] = (f16)((ph ? dR : eR)[rem]);
  } else {
    int idx = (bx - 2986) * 256 + tid;          // awh[ph][n][d]
    if (idx < 2 * NN * DD) {
      int ph = idx / (NN * DD);
      int rem = idx - ph * (NN * DD);
      awh[idx] = (f16)((ph ? daw : eaw)[rem]);
    }
  }
}

// ---------- init: zcat(0), wf(0) ----------
__global__ __launch_bounds__(256) void k_z0(const float* __restrict__ hist,
                                            const float* __restrict__ uv,
                                            f16* __restrict__ zout,
                                            f16* __restrict__ wfout) {
  int col = blockIdx.x;               // b*64+d
  int b = col >> 6, d = col & 63;
  float u[5], v[5];
  #pragma unroll
  for (int m = 0; m < 5; m++) { u[m] = uv[m * 64 + d]; v[m] = uv[320 + m * 64 + d]; }
  for (int n = threadIdx.x; n < NP; n += 256) {
    bool valid = n < NN;
    float hv = valid ? hist[(size_t)b * LL * NN + n] : 0.f;
    #pragma unroll
    for (int m = 1; m < 5; m++)
      zout[(size_t)col * KBIG + (m - 1) * NP + n] = valid ? (f16)(hv * u[m] + v[m]) : (f16)0.f;
    wfout[(size_t)col * NP + n] = valid ?
      (f16)((hv * u[0] + v[0]) - (hv * u[2] + v[2]) - (hv * u[4] + v[4])) : (f16)0.f;
  }
}

// ---------- transition: recompute score dots with decoder att_w ----------
__global__ __launch_bounds__(256) void k_trans(const f16* __restrict__ hxh,
                                               const float* __restrict__ daw,
                                               float* __restrict__ D) {
  int p = blockIdx.x, b = blockIdx.y, q = blockIdx.z, tid = threadIdx.x;
  const f16* h = hxh + ((size_t)p * BB + b) * NN * DD;
  int base = q * 14128;
  float s = 0.f;
  for (int i = base + tid; i < base + 14128; i += 256) s += (float)h[i] * daw[i];
  __shared__ float red[256];
  red[tid] = s; __syncthreads();
  for (int st = 128; st; st >>= 1) { if (tid < st) red[tid] += red[tid + st]; __syncthreads(); }
  if (tid == 0) atomicAdd(&D[(12 + p) * 32 + b], red[0]);
}

// ---------- K1: main diffusion GEMM, K-split x2, 448 blocks ----------
__global__ __launch_bounds__(256, 2) void k_gemm(
    const f16* __restrict__ Sbig, const f16* __restrict__ zin,
    f16* __restrict__ bdh) {
  __shared__ __align__(16) char smem[49152];   // sA dbuf 2x16KB | sB dbuf 2x8KB
  char* sAc = smem;
  char* sBc = smem + 32768;
  int flat = blockIdx.x;
  int xcd = flat & 7, j = flat >> 3;
  int G = xcd * 56 + j;                         // b-major XCD grouping (bijective)
  int b = G / 14, rem = G % 14;
  int kc = rem / 7, br = (rem % 7) * 128;
  const int kbase = kc * 1792;
  int tid = threadIdx.x, lane = tid & 63, w = tid >> 6;
  int l15 = lane & 15, l16 = lane >> 4, x7 = l15 & 7;
  int wr = (w >> 1) * 64, wc = (w & 1) * 32;
  int srow = lane >> 3;
  int sslot = (lane & 7) ^ (srow & 7);          // pre-swizzled source slot

  auto STAGE = [&](int it, int buf) {
    const f16* gA = Sbig + (size_t)br * KBIG + kbase + it * 64;
    #pragma unroll
    for (int o = 0; o < 4; o++) {
      int rg = (w * 4 + o) * 8;
      GLL16(gA + (size_t)(rg + srow) * KBIG + sslot * 8, sAc + buf * 16384 + rg * 128);
    }
    const f16* gB = zin + (size_t)(b * 64) * KBIG + kbase + it * 64;
    #pragma unroll
    for (int o = 0; o < 2; o++) {
      int rg = (w * 2 + o) * 8;
      GLL16(gB + (size_t)(rg + srow) * KBIG + sslot * 8, sBc + buf * 8192 + rg * 128);
    }
  };

  f32x4 acc[4][2] = {};
  STAGE(0, 0);
  for (int it = 0; it < 28; ++it) {
    int cur = it & 1;
    if (it + 1 < 28) {
      STAGE(it + 1, cur ^ 1);
      asm volatile("s_waitcnt vmcnt(6)" ::: "memory");
    } else {
      asm volatile("s_waitcnt vmcnt(0)" ::: "memory");
    }
    __builtin_amdgcn_s_barrier();
    #pragma unroll
    for (int kk = 0; kk < 2; kk++) {
      int q = kk * 4 + l16;
      f16x8 af[4], bf[2];
      #pragma unroll
      for (int fr = 0; fr < 4; fr++) {
        int row = wr + fr * 16 + l15;
        af[fr] = *(const f16x8*)(sAc + cur * 16384 + row * 128 + ((q ^ x7) << 4));
      }
      #pragma unroll
      for (int fc = 0; fc < 2; fc++) {
        int row = wc + fc * 16 + l15;
        bf[fc] = *(const f16x8*)(sBc + cur * 8192 + row * 128 + ((q ^ x7) << 4));
      }
      #pragma unroll
      for (int fr = 0; fr < 4; fr++)
        #pragma unroll
        for (int fc = 0; fc < 2; fc++)
          acc[fr][fc] = __builtin_amdgcn_mfma_f32_16x16x32_f16(af[fr], bf[fc], acc[fr][fc], 0, 0, 0);
    }
    __builtin_amdgcn_s_barrier();
  }
  f16* out = bdh + (size_t)kc * ((size_t)2048 * NP);
  #pragma unroll
  for (int fr = 0; fr < 4; fr++)
    #pragma unroll
    for (int fc = 0; fc < 2; fc++) {
      int n = br + wr + fr * 16 + l16 * 4;
      int d = wc + fc * 16 + l15;
      f16x4 hv;
      #pragma unroll
      for (int r = 0; r < 4; r++) hv[r] = (f16)acc[fr][fc][r];
      *(f16x4*)&out[(size_t)(b * 64 + d) * NP + n] = hv;
    }
}

// ---------- K2: cell finish + fused z-GEMM for t+1, 896 blocks (32-node tiles) ----------
__global__ __launch_bounds__(256, 4) void k_fin(
    int t, int phase, int zmode,
    const f16* __restrict__ bdh, const f16* __restrict__ wfin,
    const float* __restrict__ gb,
    float* __restrict__ D, const float* __restrict__ rdot,
    f16* __restrict__ hxh, float* __restrict__ prevf,
    const f16* __restrict__ Rh, const f16* __restrict__ awh,
    const f16* __restrict__ eo_in, f16* __restrict__ eo_out,
    const f16* __restrict__ W2t, const float* __restrict__ uv,
    const float* __restrict__ hist,
    f16* __restrict__ zout, f16* __restrict__ wfout,
    float* __restrict__ dout, const float* __restrict__ pw, const float* __restrict__ pb) {
  __shared__ float lsf[32 * 64];   // conv-pre, transposed+swizzled
  __shared__ f16 ls2h[32 * 64];    // outp f16, swizzled for z-GEMM A-frags
  __shared__ float redw[4];
  int flat = blockIdx.x;
  int xcd = flat & 7, jj = flat >> 3;
  int G = xcd * 112 + jj;          // 896 = 8*112, bijective
  int b = G / 28, nt = G % 28;
  int n0 = nt * 32, c0 = b * 64;
  int tid = threadIdx.x, lane = tid & 63, w = tid >> 6;
  int l15 = lane & 15, l16 = lane >> 4, x7 = l15 & 7;

  // softmax weights (redundant per thread)
  float wk[6];
  {
    float sc[6], mx = -1e30f;
    #pragma unroll
    for (int k = 0; k < 6; k++) { sc[k] = D[(t + k) * 32 + b] + rdot[phase * 6 + k]; mx = fmaxf(mx, sc[k]); }
    float se = 0.f;
    #pragma unroll
    for (int k = 0; k < 6; k++) { sc[k] = __expf(sc[k] - mx); se += sc[k]; }
    float inv = 1.f / se;
    #pragma unroll
    for (int k = 0; k < 6; k++) wk[k] = sc[k] * inv;
  }

  // phase A: conv-pre = bd0+bd1+wf+gb, transpose into lsf
  {
    int col = tid >> 2, ns = tid & 3;
    size_t base = (size_t)(c0 + col) * NP + n0 + ns * 8;
    f16x8 p0 = *(const f16x8*)&bdh[base];
    f16x8 p1 = *(const f16x8*)&bdh[(size_t)2048 * NP + base];
    f16x8 wv = *(const f16x8*)&wfin[base];
    float gbv = gb[col];
    #pragma unroll
    for (int jx = 0; jx < 8; jx++) {
      float s = (float)p0[jx] + (float)p1[jx] + (float)wv[jx] + gbv;
      int n_ = ns * 8 + jx;
      lsf[n_ * 64 + (col ^ (n_ & 7))] = s;
    }
  }
  __syncthreads();

  // phase B: cell finish — thread = (row = tid>>3, d-octet q = tid&7); all wide loads
  int slotW = t % 6;
  const size_t plane = (size_t)BB * NN * DD;
  {
    int row = tid >> 3, q = tid & 7;
    int n = n0 + row, d0 = q * 8;
    bool valid = n < NN;
    size_t hb = ((size_t)b * NN + n) * DD + d0;
    f16x8 zz = {};
    f16x8 hp[5], rk[6], awv;
    f32x4 pv0 = {}, pv1 = {};
    if (valid) {
      #pragma unroll
      for (int k = 0; k < 5; k++)
        hp[k] = (t + k >= 6) ? *(const f16x8*)&hxh[(size_t)((t + k) % 6) * plane + hb] : zz;
      if (t >= 1) { pv0 = *(const f32x4*)&prevf[hb]; pv1 = *(const f32x4*)&prevf[hb + 4]; }
      #pragma unroll
      for (int k = 0; k < 6; k++)
        rk[k] = *(const f16x8*)&Rh[(((size_t)phase * 6 + k) * NN + n) * DD + d0];
      awv = *(const f16x8*)&awh[((size_t)phase * NN + n) * DD + d0];
    } else {
      #pragma unroll
      for (int k = 0; k < 5; k++) hp[k] = zz;
      #pragma unroll
      for (int k = 0; k < 6; k++) rk[k] = zz;
      awv = zz;
    }
    f32x4 pw0 = *(const f32x4*)&pw[d0];
    f32x4 pw1 = *(const f32x4*)&pw[d0 + 4];
    float dsum = 0.f, psum = 0.f;
    f16x8 houtv = zz, eov = zz;
    f32x4 np0 = {}, np1 = {};
    #pragma unroll
    for (int jx = 0; jx < 8; jx++) {
      int d = d0 + jx;
      float conv = lsf[row * 64 + (d ^ (row & 7))];
      conv = conv > 0.f ? conv : 0.01f * conv;
      float prev = (jx < 4) ? pv0[jx & 3] : pv1[jx & 3];
      float att = 0.f;
      #pragma unroll
      for (int k = 0; k < 5; k++) att += wk[k] * ((float)hp[k][jx] + (float)rk[k][jx]);
      float s5 = prev + (float)rk[5][jx];
      att += wk[5] * s5;
      float outp = s5 + conv;
      if (jx < 4) np0[jx & 3] = outp; else np1[jx & 3] = outp;
      houtv[jx] = (f16)outp;
      float oc = outp + att;
      dsum += outp * (float)awv[jx];
      if (!phase) eov[jx] = (f16)oc;
      else psum += oc * ((jx < 4) ? pw0[jx & 3] : pw1[jx & 3]);
    }
    if (valid) {
      *(f16x8*)&hxh[(size_t)slotW * plane + hb] = houtv;
      *(f32x4*)&prevf[hb] = np0;
      *(f32x4*)&prevf[hb + 4] = np1;
      if (!phase) *(f16x8*)&eo_out[((size_t)b * NP + n) * DD + d0] = eov;
    }
    *(f16x8*)&ls2h[row * 64 + ((q ^ (row & 7)) << 3)] = houtv;
    if (phase) {
      psum += __shfl_xor(psum, 1);
      psum += __shfl_xor(psum, 2);
      psum += __shfl_xor(psum, 4);
      if (valid && q == 0) dout[((size_t)b * HH + (t - LL)) * NN + n] = psum + pb[0];
    }
    #pragma unroll
    for (int s = 32; s; s >>= 1) dsum += __shfl_xor(dsum, s);
    if (lane == 0) redw[w] = dsum;
  }
  __syncthreads();
  if (tid == 0) atomicAdd(&D[(6 + t) * 32 + b], redw[0] + redw[1] + redw[2] + redw[3]);

  // phase C: z-GEMM for step t+1 (warp w: A-strip w&1, fb-pair w>>1)
  if (zmode) {
    const int ZKW = (zmode == 2) ? 128 : 64;
    const int kh32 = (zmode == 2) ? 2 : 0;
    int fa = w & 1, fbs = (w >> 1) * 2;
    f16x8 afh[2];
    #pragma unroll
    for (int kk = 0; kk < 2; kk++) {
      int row = fa * 16 + l15;
      afh[kk] = *(const f16x8*)&ls2h[row * 64 + (((kk * 4 + l16) ^ x7) << 3)];
    }
    f16x8 afe[2];
    if (zmode == 2) {
      #pragma unroll
      for (int kk = 0; kk < 2; kk++)
        afe[kk] = *(const f16x8*)&eo_in[((size_t)b * NP + n0 + fa * 16 + l15) * 64 + kk * 32 + l16 * 8];
    }
    float hv_[4];
    if (zmode == 1) {
      #pragma unroll
      for (int r = 0; r < 4; r++) {
        int n = n0 + fa * 16 + l16 * 4 + r;
        hv_[r] = (n < NN) ? hist[((size_t)b * LL + (t + 1)) * NN + n] : 0.f;
      }
    }
    f32x4 wacc[2];
    #pragma unroll
    for (int m = 0; m < 5; m++) {
      f32x4 zacc[2] = {};
      #pragma unroll
      for (int kk = 0; kk < 2; kk++)
        #pragma unroll
        for (int fbi = 0; fbi < 2; fbi++) {
          f16x8 bfv = *(const f16x8*)&W2t[(size_t)(m * 64 + (fbs + fbi) * 16 + l15) * ZKW + (kh32 + kk) * 32 + l16 * 8];
          zacc[fbi] = __builtin_amdgcn_mfma_f32_16x16x32_f16(afh[kk], bfv, zacc[fbi], 0, 0, 0);
        }
      if (zmode == 2) {
        #pragma unroll
        for (int kk = 0; kk < 2; kk++)
          #pragma unroll
          for (int fbi = 0; fbi < 2; fbi++) {
            f16x8 bfv = *(const f16x8*)&W2t[(size_t)(m * 64 + (fbs + fbi) * 16 + l15) * ZKW + kk * 32 + l16 * 8];
            zacc[fbi] = __builtin_amdgcn_mfma_f32_16x16x32_f16(afe[kk], bfv, zacc[fbi], 0, 0, 0);
          }
      }
      if (zmode == 1) {
        #pragma unroll
        for (int fbi = 0; fbi < 2; fbi++) {
          float u = uv[m * 64 + (fbs + fbi) * 16 + l15];
          float v = uv[320 + m * 64 + (fbs + fbi) * 16 + l15];
          #pragma unroll
          for (int r = 0; r < 4; r++) zacc[fbi][r] += hv_[r] * u + v;
        }
      }
      if (m == 0) {
        wacc[0] = zacc[0]; wacc[1] = zacc[1];
      } else {
        if (m == 2 || m == 4) {
          #pragma unroll
          for (int fbi = 0; fbi < 2; fbi++)
            #pragma unroll
            for (int r = 0; r < 4; r++) wacc[fbi][r] -= zacc[fbi][r];
        }
        #pragma unroll
        for (int fbi = 0; fbi < 2; fbi++) {
          int n = n0 + fa * 16 + l16 * 4;
          int d = (fbs + fbi) * 16 + l15;
          f16x4 hv4;
          #pragma unroll
          for (int r = 0; r < 4; r++) hv4[r] = (f16)zacc[fbi][r];
          *(f16x4*)&zout[(size_t)(c0 + d) * KBIG + (m - 1) * NP + n] = hv4;
        }
      }
    }
    #pragma unroll
    for (int fbi = 0; fbi < 2; fbi++) {
      int n = n0 + fa * 16 + l16 * 4;
      int d = (fbs + fbi) * 16 + l15;
      f16x4 wv4;
      #pragma unroll
      for (int r = 0; r < 4; r++) wv4[r] = (f16)wacc[fbi][r];
      *(f16x4*)&wfout[(size_t)(c0 + d) * NP + n] = wv4;
    }
  }
}

// ---------------- host ----------------
extern "C" void kernel_launch(void* const* d_in, const int* in_sizes, int n_in,
                              void* d_out, int out_size, void* d_ws, size_t ws_size,
                              hipStream_t stream) {
  (void)in_sizes; (void)n_in; (void)out_size; (void)ws_size;
  const float* hist = (const float*)d_in[0];
  const float* adj  = (const float*)d_in[1];
  const float* emw  = (const float*)d_in[2];
  const float* emb  = (const float*)d_in[3];
  const float* egw  = (const float*)d_in[4];
  const float* egb  = (const float*)d_in[5];
  const float* eR   = (const float*)d_in[6];
  const float* eaw  = (const float*)d_in[7];
  const float* dgw  = (const float*)d_in[9];
  const float* dgb  = (const float*)d_in[10];
  const float* dR   = (const float*)d_in[11];
  const float* daw  = (const float*)d_in[12];
  const float* pw   = (const float*)d_in[14];
  const float* pb   = (const float*)d_in[15];

  char* wsp = (char*)d_ws;
  size_t off = 0;
  auto take = [&](size_t bytes) { char* p = wsp + off; off = (off + bytes + 255) & ~(size_t)255; return p; };
  f16*   Sbig  = (f16*)  take((size_t)NP * KBIG * 2);
  f16*   S1T   = (f16*)  take((size_t)NP * NP * 2);
  f16*   S2T   = (f16*)  take((size_t)NP * NP * 2);
  float* invr  = (float*)take(NP * 4);
  float* csum  = (float*)take(NP * 4);
  f16*   W2te  = (f16*)  take(5 * 64 * 64 * 2);
  f16*   W2td  = (f16*)  take(5 * 64 * 128 * 2);
  float* uv    = (float*)take(640 * 4);
  float* rdot  = (float*)take(256);
  float* D     = (float*)take(30 * 32 * 4);
  f16*   hxh   = (f16*)  take(6ULL * BB * NN * DD * 2);
  float* prevf = (float*)take((size_t)BB * NN * DD * 4);
  f16*   Rh    = (f16*)  take(2ULL * 6 * NN * DD * 2);
  f16*   awh   = (f16*)  take(2ULL * NN * DD * 2);
  f16*   eoh   = (f16*)  take(12ULL * ZSL * 2);
  f16*   zc0   = (f16*)  take(2048ULL * KBIG * 2);
  f16*   zc1   = (f16*)  take(2048ULL * KBIG * 2);
  f16*   wfh0  = (f16*)  take(2048ULL * NP * 2);
  f16*   wfh1  = (f16*)  take(2048ULL * NP * 2);
  f16*   bdh   = (f16*)  take(2ULL * 2048 * NP * 2);

  hipMemsetAsync(D, 0, 30 * 32 * 4, stream);
  hipMemsetAsync(rdot, 0, 256, stream);
  hipMemsetAsync(csum, 0, NP * 4, stream);

  k_sums<<<dim3(445), 256, 0, stream>>>(adj, invr, csum);
  k_sprep2<<<dim3(14, 14), 256, 0, stream>>>(adj, invr, csum, Sbig, S1T, S2T);
  k_ssq<<<dim3(7, 7, 2), 256, 0, stream>>>(Sbig, S1T, S2T);
  k_wprep<<<dim3(3428), 256, 0, stream>>>(egw, dgw, emw, emb, eR, dR, eaw, daw,
                                          W2te, W2td, uv, rdot, Rh, awh);
  k_z0<<<dim3(2048), 256, 0, stream>>>(hist, uv, zc0, wfh0);

  f16* zc[2] = {zc0, zc1};
  f16* wf[2] = {wfh0, wfh1};
  for (int t = 0; t < 24; t++) {
    int ph = (t >= 12) ? 1 : 0;
    int zmode = (t == 23) ? 0 : ((t + 1 >= 12) ? 2 : 1);
    k_gemm<<<dim3(448), 256, 0, stream>>>(Sbig, zc[t & 1], bdh);
    if (t == 12) {
      hipMemsetAsync((char*)(D + 12 * 32), 0, 6 * 32 * 4, stream);
      k_trans<<<dim3(6, 32, 4), 256, 0, stream>>>(hxh, daw, D);
    }
    k_fin<<<dim3(896), 256, 0, stream>>>(
        t, ph, zmode, bdh, wf[t & 1], ph ? dgb : egb,
        D, rdot, hxh, prevf, Rh, awh,
        (zmode == 2) ? (eoh + (size_t)(t + 1 - 12) * ZSL) : eoh,
        ph ? eoh : (eoh + (size_t)t * ZSL),
        (t + 1 < 12) ? W2te : W2td, uv, hist,
        zc[(t + 1) & 1], wf[(t + 1) & 1], (float*)d_out, pw, pb);
  }
}